// Round 17
// baseline (127.061 us; speedup 1.0000x reference)
//
#include <hip/hip_runtime.h>

typedef __attribute__((ext_vector_type(8))) short short8;
typedef __attribute__((ext_vector_type(8))) _Float16 half8;
typedef __attribute__((ext_vector_type(4))) float f32x4;
typedef __attribute__((ext_vector_type(16))) float f32x16;
typedef __attribute__((ext_vector_type(4))) unsigned short us4;
typedef __attribute__((ext_vector_type(4))) unsigned int u32x4;

#define MFMA16(a,b,c)  __builtin_amdgcn_mfma_f32_16x16x32_bf16(a,b,c,0,0,0)
#define MFMA32(a,b,c)  __builtin_amdgcn_mfma_f32_32x32x16_bf16(a,b,c,0,0,0)
#define MFMA32H(a,b,c) __builtin_amdgcn_mfma_f32_32x32x16_f16(a,b,c,0,0,0)

#define EMBED 768
#define HEADS 12
#define DK 64
#define M_MISS 2048
#define N_EX 6144
#define NSEC 8192
#define DPHY 128              // physical packed dim: [0,64)=proj bf16, [64,128)=bias f16
#define QSC 0.125f            // Q-side scale (natural-log domain; __expf native exp path)
#define THR 7.0f              // defer-max threshold (P <= e^7 ~ 1100)

// direct global->LDS, 16B per lane; dest = wave-uniform base + lane*16
#define GLOAD16(g, l) __builtin_amdgcn_global_load_lds( \
    (const __attribute__((address_space(1))) unsigned int*)(g), \
    (__attribute__((address_space(3))) unsigned int*)(l), 16, 0, 0)

__device__ __forceinline__ unsigned short f2bf(float f){
  unsigned u = __builtin_bit_cast(unsigned, f);
  u += 0x7FFFu + ((u >> 16) & 1u);
  return (unsigned short)(u >> 16);
}
__device__ __forceinline__ float bf2f(unsigned short h){
  return __builtin_bit_cast(float, ((unsigned)h) << 16);
}
__device__ __forceinline__ unsigned short f2h(float f){
  _Float16 h = (_Float16)f;      // RNE, 10 mantissa bits — 8x tighter than bf16
  return __builtin_bit_cast(unsigned short, h);
}
__device__ __forceinline__ float max3(float a, float b, float c){
  return fmaxf(fmaxf(a, b), c);  // clang fuses to v_max3_f32
}

// ---------------- setup: ehrb <- bf16(ehr), Wt transpose (gemm dependencies ONLY) ----------------
__global__ __launch_bounds__(256) void k_setup(
    const float* __restrict__ ehr, unsigned short* __restrict__ ehrb,
    const float* __restrict__ Wq, const float* __restrict__ Wk,
    const float* __restrict__ Wv, unsigned short* __restrict__ Wt)
{
  __shared__ float tile[64][65];
  int b = blockIdx.x, tid = threadIdx.x;
  if (b < 3072) {
    long g = (long)b * 256 + tid;
    float4 v0 = *reinterpret_cast<const float4*>(&ehr[g * 8]);
    float4 v1 = *reinterpret_cast<const float4*>(&ehr[g * 8 + 4]);
    short8 p;
    p[0]=(short)f2bf(v0.x); p[1]=(short)f2bf(v0.y); p[2]=(short)f2bf(v0.z); p[3]=(short)f2bf(v0.w);
    p[4]=(short)f2bf(v1.x); p[5]=(short)f2bf(v1.y); p[6]=(short)f2bf(v1.z); p[7]=(short)f2bf(v1.w);
    *reinterpret_cast<short8*>(&ehrb[g * 8]) = p;
    return;
  }
  int bid = b - 3072;
  int which = bid / 144, t = bid % 144;
  int er0 = (t / 12) * 64, cc0 = (t % 12) * 64;
  const float* W = (which == 0) ? Wq : ((which == 1) ? Wk : Wv);
  unsigned short* dst = Wt + (long)which * EMBED * EMBED;
  {
    int e = tid >> 4, c4 = (tid & 15) * 4;
    for (int i = 0; i < 4; i++) {
      float4 v = *reinterpret_cast<const float4*>(&W[(long)(er0 + e + i*16) * EMBED + cc0 + c4]);
      tile[e + i*16][c4 + 0] = v.x; tile[e + i*16][c4 + 1] = v.y;
      tile[e + i*16][c4 + 2] = v.z; tile[e + i*16][c4 + 3] = v.w;
    }
  }
  __syncthreads();
  {
    int c = tid >> 4, e4 = (tid & 15) * 4;
    for (int i = 0; i < 4; i++) {
      us4 u;
      for (int j = 0; j < 4; j++) u[j] = f2bf(tile[e4 + j][c + i*16]);
      *reinterpret_cast<us4*>(&dst[(long)(cc0 + c + i*16) * EMBED + er0 + e4]) = u;
    }
  }
}

// ---------------- fused gather-GEMM + (appended) cooc f16 pack + exist-rows out copy ----------------
// [0,672): Q/K/V gemm. [672,2208): Qp cooc pack. [2208,6816): Kp cooc pack.
// [6816,8352): out[exist rows] <- ehr (missing rows written later by k_merge — race-free).
__global__ __launch_bounds__(256) void k_gemm_fused(
    const unsigned short* __restrict__ ehrb,
    const int* __restrict__ missing, const int* __restrict__ exist,
    const unsigned short* __restrict__ Wt,
    const float* __restrict__ bq, const float* __restrict__ bk, const float* __restrict__ bv,
    unsigned short* __restrict__ Qp, unsigned short* __restrict__ Kp, unsigned short* __restrict__ Vt,
    const float* __restrict__ cooc, const float* __restrict__ ehr, float* __restrict__ out)
{
  __shared__ unsigned char sA[2][8192];   // 128 rows x 32 bf16 (64B rows), chunk-swizzled
  __shared__ unsigned char sB[2][8192];
  int bid = blockIdx.x;
  int tid = threadIdx.x;

  if (bid >= 6816) {       // exist-rows copy: 1536 blocks x 4 rows
    int t4 = (bid - 6816) * 4 + (tid >> 6);
    long row = exist[t4];
    const f32x4* s = reinterpret_cast<const f32x4*>(ehr + row * EMBED);
    f32x4* d = reinterpret_cast<f32x4*>(out + row * EMBED);
    int l = tid & 63;
    d[l] = s[l]; d[l + 64] = s[l + 64]; d[l + 128] = s[l + 128];
    return;
  }
  if (bid >= 672) {        // cooc f16 pack into dims [64,128) of Qp/Kp
    const int* idx; unsigned short* dst; int count; int g;
    if (bid < 2208) { idx = missing; dst = Qp; count = M_MISS; g = (bid -  672) * 256 + tid; }
    else            { idx = exist;   dst = Kp; count = N_EX;   g = (bid - 2208) * 256 + tid; }
    int d4 = (g & 15) * 4;
    int r  = (g >> 4) % count;
    int h  = (g >> 4) / count;
    int src_row = idx[r];
    float4 v = *reinterpret_cast<const float4*>(&cooc[((long)h * NSEC + src_row) * DK + d4]);
    us4 hf;
    hf[0] = f2h(v.x); hf[1] = f2h(v.y); hf[2] = f2h(v.z); hf[3] = f2h(v.w);
    long base = ((long)h * count + r) * DPHY;
    *reinterpret_cast<us4*>(&dst[base + 64 + d4]) = hf;
    return;
  }

  int mode, row0, col0;
  const int* idx; const unsigned short* W; const float* bias;
  if (bid < 96)       { mode = 0; idx = missing; W = Wt;              bias = bq;
                        row0 = (bid & 15) * 128; col0 = (bid >> 4) * 128; }
  else if (bid < 384) { int t = bid - 96;  mode = 1; idx = exist; W = Wt + 589824;     bias = bk;
                        row0 = (t % 48) * 128; col0 = (t / 48) * 128; }
  else                { int t = bid - 384; mode = 2; idx = exist; W = Wt + 2 * 589824; bias = bv;
                        row0 = (t % 48) * 128; col0 = (t / 48) * 128; }

  int wv4 = tid >> 6, lane = tid & 63, l15 = lane & 15, lg = lane >> 4;
  int wm = wv4 >> 1, wn = wv4 & 1;

  int ar = tid >> 2, sl = tid & 3;
  int aoff = (sl ^ (ar & 3)) << 3;                     // element offset within row
  long gA0 = (long)idx[row0 + ar] * EMBED + aoff;
  long gA1 = (long)idx[row0 + ar + 64] * EMBED + aoff; // (ar+64)&3 == ar&3
  long gB0 = (long)(col0 + ar) * EMBED + aoff;
  long gB1 = gB0 + (long)64 * EMBED;

  f32x4 acc[4][4];
  #pragma unroll
  for (int i = 0; i < 4; i++)
    #pragma unroll
    for (int j = 0; j < 4; j++) acc[i][j] = (f32x4){0.f,0.f,0.f,0.f};

  #define STAGE_G(buf, k0) do { \
    GLOAD16(ehrb + gA0 + (k0), &sA[buf][wv4 * 1024]); \
    GLOAD16(ehrb + gA1 + (k0), &sA[buf][4096 + wv4 * 1024]); \
    GLOAD16(W + gB0 + (k0), &sB[buf][wv4 * 1024]); \
    GLOAD16(W + gB1 + (k0), &sB[buf][4096 + wv4 * 1024]); \
  } while (0)

  STAGE_G(0, 0);
  __syncthreads();
  int cur = 0;
  for (int ks = 0; ks < 24; ks++) {
    if (ks < 23) STAGE_G(cur ^ 1, (ks + 1) * 32);
    short8 a[4], b[4];
    #pragma unroll
    for (int i = 0; i < 4; i++) {
      unsigned r = (unsigned)(wm * 64 + 16 * i + l15);
      a[i] = *reinterpret_cast<const short8*>(&sA[cur][r * 64 + (((unsigned)lg ^ (r & 3)) << 4)]);
      unsigned c = (unsigned)(wn * 64 + 16 * i + l15);
      b[i] = *reinterpret_cast<const short8*>(&sB[cur][c * 64 + (((unsigned)lg ^ (c & 3)) << 4)]);
    }
    #pragma unroll
    for (int i = 0; i < 4; i++)
      #pragma unroll
      for (int j = 0; j < 4; j++)
        acc[i][j] = MFMA16(a[i], b[j], acc[i][j]);
    __syncthreads();
    cur ^= 1;
  }
  #undef STAGE_G

  #pragma unroll
  for (int i = 0; i < 4; i++) {
    int mrow = row0 + wm * 64 + 16 * i + lg * 4;
    #pragma unroll
    for (int j = 0; j < 4; j++) {
      int cg = col0 + wn * 64 + 16 * j + l15;
      float bv_ = bias[cg];
      int h = cg >> 6, d = cg & 63;
      if (mode == 2) {
        us4 u;
        #pragma unroll
        for (int r = 0; r < 4; r++) u[r] = f2bf(acc[i][j][r] + bv_);
        *reinterpret_cast<us4*>(&Vt[((long)h * 64 + d) * N_EX + mrow]) = u;
      } else if (mode == 0) {
        #pragma unroll
        for (int r = 0; r < 4; r++)
          Qp[((long)h * M_MISS + mrow + r) * DPHY + d] = f2bf((acc[i][j][r] + bv_) * QSC);
      } else {
        #pragma unroll
        for (int r = 0; r < 4; r++)
          Kp[((long)h * N_EX + mrow + r) * DPHY + d] = f2bf(acc[i][j][r] + bv_);
      }
    }
  }
}

// ---------------- flash attention: swapped 32x32 MFMA, in-register softmax ----------------
// Inner loop FROZEN at r14/r16 measured-best. NS=8: grid 1536 = 6 blocks/CU (LDS 24KB and
// VGPR 84 both allow 6) — removes the grid-bound occupancy cap (was 3/CU at NS=4).
// r7's NS=8 regression was the OLD 32KB kernel: 5/CU cap -> ragged 1.2 generations + fp32
// partial traffic; both fixed here (clean 6/CU generation, bf16 partials).
template<int NS>
__global__ __launch_bounds__(256, 3) void k_attn(
    const unsigned short* __restrict__ Qp, const unsigned short* __restrict__ Kp,
    const unsigned short* __restrict__ Vt,
    unsigned short* __restrict__ Opart, float* __restrict__ ML)
{
  // XCD-chunked swizzle: nwg = 192*NS, divisible by 8
  constexpr int NSLc = N_EX / NS;
  constexpr int ITERS = NSLc / 64;
  int cpx = 24 * NS;
  int wg = (blockIdx.x & 7) * cpx + (blockIdx.x >> 3);
  int per_h = NS << 4;
  int h  = wg / per_h;
  int rem = wg - h * per_h;
  int sp = rem >> 4;
  int qb = rem & 15;
  int tid = threadIdx.x;
  int wv = tid >> 6, lane = tid & 63, l31 = lane & 31, hh = lane >> 5;

  __shared__ unsigned char sK[64 * 256];   // 64 n-rows x 128 shorts (16 chunks), 4-bit swizzle: 16KB
  __shared__ unsigned char sV[64 * 128];   // 64 d-rows x  64 bf16  ( 8 chunks), 3-bit swizzle:  8KB

  int koff[4];
  #pragma unroll
  for (int i = 0; i < 4; i++) {
    int s = i * 256 + tid;
    int row = s >> 4, slt = s & 15;
    koff[i] = row * DPHY + ((slt ^ (row & 15)) << 3);
  }
  int voff[2];
  #pragma unroll
  for (int i = 0; i < 2; i++) {
    int s = i * 256 + tid;
    int row = s >> 3, slt = s & 7;
    voff[i] = row * N_EX + ((slt ^ (row & 7)) << 3);
  }
  const unsigned short* kti0 = Kp + ((long)h * N_EX + sp * NSLc) * DPHY;
  const unsigned short* vti0 = Vt + (long)h * 64 * N_EX + sp * NSLc;

  int mbase = qb * 128 + wv * 32;
  int m = mbase + l31;

  short8 qg[8];
  {
    const unsigned short* qrow = Qp + ((long)h * M_MISS + m) * DPHY + hh * 8;
    #pragma unroll
    for (int g = 0; g < 8; g++)
      qg[g] = *reinterpret_cast<const short8*>(qrow + g * 16);
  }

  f32x16 oacc[2];
  #pragma unroll
  for (int dt = 0; dt < 2; dt++)
    #pragma unroll
    for (int r = 0; r < 16; r++) oacc[dt][r] = 0.f;
  float m_run = -3.0e38f, l_run = 0.f;

  for (int it = 0; it < ITERS; ++it) {
    __syncthreads();   // all waves done reading previous tile
    {
      const unsigned short* kt_ = kti0 + (long)it * 64 * DPHY;
      GLOAD16(kt_ + koff[0], &sK[(0 * 4 + wv) * 1024]);
      GLOAD16(kt_ + koff[1], &sK[(1 * 4 + wv) * 1024]);
      GLOAD16(kt_ + koff[2], &sK[(2 * 4 + wv) * 1024]);
      GLOAD16(kt_ + koff[3], &sK[(3 * 4 + wv) * 1024]);
      const unsigned short* vt_ = vti0 + it * 64;
      GLOAD16(vt_ + voff[0], &sV[(0 * 4 + wv) * 1024]);
      GLOAD16(vt_ + voff[1], &sV[(1 * 4 + wv) * 1024]);
    }
    __syncthreads();   // drains vmcnt: tile ready

    // S^T: 2 n-tiles of 32 rows. A = K chunk (row n=l31), B = qg (col m=l31).
    // chunks 0-3: proj bf16; chunks 4-7: bias f16 (same fp32 accumulator).
    f32x16 st[2];
    #pragma unroll
    for (int nt = 0; nt < 2; nt++) {
      #pragma unroll
      for (int r = 0; r < 16; r++) st[nt][r] = 0.f;
      unsigned nrow = (unsigned)(nt * 32 + l31);
      const unsigned char* kb = &sK[nrow * 256];
      unsigned px = nrow & 15;
      #define KRD(g) (*reinterpret_cast<const short8*>(kb + ((((unsigned)(2*(g)+hh)) ^ px) << 4)))
      short8 kf;
      kf = KRD(0); st[nt] = MFMA32(kf, qg[0], st[nt]);
      kf = KRD(1); st[nt] = MFMA32(kf, qg[1], st[nt]);
      kf = KRD(2); st[nt] = MFMA32(kf, qg[2], st[nt]);
      kf = KRD(3); st[nt] = MFMA32(kf, qg[3], st[nt]);
      kf = KRD(4); st[nt] = MFMA32H(__builtin_bit_cast(half8, kf), __builtin_bit_cast(half8, qg[4]), st[nt]);
      kf = KRD(5); st[nt] = MFMA32H(__builtin_bit_cast(half8, kf), __builtin_bit_cast(half8, qg[5]), st[nt]);
      kf = KRD(6); st[nt] = MFMA32H(__builtin_bit_cast(half8, kf), __builtin_bit_cast(half8, qg[6]), st[nt]);
      kf = KRD(7); st[nt] = MFMA32H(__builtin_bit_cast(half8, kf), __builtin_bit_cast(half8, qg[7]), st[nt]);
      #undef KRD
    }

    // in-register online softmax (natural domain, native __expf), defer-max; v_max3 tree
    float t0 = max3(max3(st[0][0],  st[0][1],  st[0][2]),
                    max3(st[0][3],  st[0][4],  st[0][5]),
                    max3(st[0][6],  st[0][7],  st[0][8]));
    float t1 = max3(max3(st[0][9],  st[0][10], st[0][11]),
                    max3(st[0][12], st[0][13], st[0][14]),
                    max3(st[0][15], st[1][0],  st[1][1]));
    float t2 = max3(max3(st[1][2],  st[1][3],  st[1][4]),
                    max3(st[1][5],  st[1][6],  st[1][7]),
                    max3(st[1][8],  st[1][9],  st[1][10]));
    float t3 = max3(max3(st[1][11], st[1][12], st[1][13]),
                    fmaxf(st[1][14], st[1][15]), t0);
    float mx = max3(t1, t2, t3);
    mx = fmaxf(mx, __shfl_xor(mx, 32));
    if (!__all(mx <= m_run + THR)) {
      float mn = fmaxf(m_run, mx);
      float sc = __expf(m_run - mn);
      m_run = mn;
      l_run *= sc;
      #pragma unroll
      for (int dt = 0; dt < 2; dt++)
        #pragma unroll
        for (int r = 0; r < 16; r++) oacc[dt][r] *= sc;
    }
    float lsum = 0.f;
    unsigned c[2][4][2];   // c[nt][jj][i] = bf16pair P(nt*32+8jj+4hh+2i, +1)
    #pragma unroll
    for (int nt = 0; nt < 2; nt++) {
      float p[16];
      #pragma unroll
      for (int r = 0; r < 16; r++) { p[r] = __expf(st[nt][r] - m_run); lsum += p[r]; }
      #pragma unroll
      for (int jj = 0; jj < 4; jj++) {
        asm("v_cvt_pk_bf16_f32 %0, %1, %2" : "=v"(c[nt][jj][0]) : "v"(p[4*jj+0]), "v"(p[4*jj+1]));
        asm("v_cvt_pk_bf16_f32 %0, %1, %2" : "=v"(c[nt][jj][1]) : "v"(p[4*jj+2]), "v"(p[4*jj+3]));
      }
    }
    lsum += __shfl_xor(lsum, 32);
    l_run += lsum;

    // P^T B-frags via permlane32_swap: newA={A_lo,B_lo}, newB={A_hi,B_hi}
    short8 pf[2][2];
    #pragma unroll
    for (int nt = 0; nt < 2; nt++)
      #pragma unroll
      for (int ks = 0; ks < 2; ks++) {
        unsigned a0 = c[nt][2*ks][0], b0 = c[nt][2*ks+1][0];
        unsigned a1 = c[nt][2*ks][1], b1 = c[nt][2*ks+1][1];
        asm("v_permlane32_swap_b32 %0, %1" : "+v"(a0), "+v"(b0));
        asm("v_permlane32_swap_b32 %0, %1" : "+v"(a1), "+v"(b1));
        u32x4 w;
        w[0] = a0; w[1] = a1; w[2] = b0; w[3] = b1;
        pf[nt][ks] = __builtin_bit_cast(short8, w);
      }

    // O^T += V^T . P^T : A = V^T (row d=l31), B = pf. 8 MFMAs.
    #pragma unroll
    for (int dt = 0; dt < 2; dt++) {
      unsigned drow = (unsigned)(dt * 32 + l31);
      const unsigned char* vb = &sV[drow * 128];
      unsigned pd = drow & 7;
      #pragma unroll
      for (int nt = 0; nt < 2; nt++)
        #pragma unroll
        for (int ks = 0; ks < 2; ks++) {
          short8 vf = *reinterpret_cast<const short8*>(vb + ((((unsigned)(nt*4+ks*2+hh)) ^ pd) << 4));
          oacc[dt] = MFMA32(vf, pf[nt][ks], oacc[dt]);
        }
    }
  }

  // epilogue: bf16 partials (fp32 range, 0.4% rel err — merges fine vs 0.101 threshold).
  // O^T reg r -> d = dt*32 + 8*(r>>2) + 4*hh + (r&3); m = mbase+l31
  long pbase = ((long)(h * NS + sp)) * M_MISS;
  if (hh == 0) {
    float2 v; v.x = m_run; v.y = l_run;
    *reinterpret_cast<float2*>(&ML[(pbase + m) * 2]) = v;
  }
  #pragma unroll
  for (int dt = 0; dt < 2; dt++)
    #pragma unroll
    for (int rq = 0; rq < 4; rq++) {
      unsigned c0, c1;
      asm("v_cvt_pk_bf16_f32 %0, %1, %2" : "=v"(c0) : "v"(oacc[dt][4*rq + 0]), "v"(oacc[dt][4*rq + 1]));
      asm("v_cvt_pk_bf16_f32 %0, %1, %2" : "=v"(c1) : "v"(oacc[dt][4*rq + 2]), "v"(oacc[dt][4*rq + 3]));
      uint2 w; w.x = c0; w.y = c1;
      *reinterpret_cast<uint2*>(&Opart[(pbase + m) * 64 + dt * 32 + 8 * rq + 4 * hh]) = w;
    }
}

// ---------------- merge split-KV bf16 partials, scatter to out (ONLY missing rows) ----------------
__global__ __launch_bounds__(256) void k_merge(
    const unsigned short* __restrict__ Opart, const float* __restrict__ ML,
    const int* __restrict__ missing, float* __restrict__ out, int ns)
{
  int g = blockIdx.x * 256 + threadIdx.x;   // HEADS*M_MISS*16
  int d4 = (g & 15) * 4;
  int row = g >> 4;
  int m = row & (M_MISS - 1), h = row >> 11;
  long b0 = (long)h * ns * M_MISS + m;
  float M = -3.0e38f;
  for (int sp = 0; sp < ns; sp++)
    M = fmaxf(M, ML[(b0 + (long)sp * M_MISS) * 2]);
  float L = 0.f;
  f32x4 o = (f32x4){0.f,0.f,0.f,0.f};
  for (int sp = 0; sp < ns; sp++) {
    float2 v = *reinterpret_cast<const float2*>(&ML[(b0 + (long)sp * M_MISS) * 2]);
    float w = __expf(v.x - M);
    L += v.y * w;
    us4 t = *reinterpret_cast<const us4*>(&Opart[(b0 + (long)sp * M_MISS) * 64 + d4]);
    o[0] += bf2f(t[0]) * w;
    o[1] += bf2f(t[1]) * w;
    o[2] += bf2f(t[2]) * w;
    o[3] += bf2f(t[3]) * w;
  }
  float inv = 1.0f / L;
  int orow = missing[m];
  *reinterpret_cast<f32x4*>(&out[(long)orow * EMBED + h * 64 + d4]) = o * inv;
}

extern "C" void kernel_launch(void* const* d_in, const int* in_sizes, int n_in,
                              void* d_out, int out_size, void* d_ws, size_t ws_size,
                              hipStream_t stream) {
  const float* ehr     = (const float*)d_in[0];
  const int*   exist   = (const int*)  d_in[1];
  const int*   missing = (const int*)  d_in[2];
  const float* Wq = (const float*)d_in[3];
  const float* bq = (const float*)d_in[4];
  const float* Wk = (const float*)d_in[5];
  const float* bk = (const float*)d_in[6];
  const float* Wv = (const float*)d_in[7];
  const float* bv = (const float*)d_in[8];
  const float* cooc = (const float*)d_in[9];
  float* out = (float*)d_out;

  const int ns = 8;   // grid 1536 = clean 6 blocks/CU generation (24KB LDS, 84 VGPR both allow 6)

  char* ws = (char*)d_ws;
  size_t opB = (size_t)HEADS * ns * M_MISS * 64 * 2;   // bf16 partials (25,165,824 — same as NS=4 fp32)
  // Wt (3.54 MB) + ehrb (12.6 MB) alias inside Opart's region (dead before k_attn writes Op).
  unsigned short* Wt   = (unsigned short*)(ws);                  // [0, 3,538,944)
  unsigned short* ehrb = (unsigned short*)(ws + 3538944);        // [3,538,944, 16,121,856)
  unsigned short* Op   = (unsigned short*)(ws);
  unsigned short* Qp = (unsigned short*)(ws + opB);              // 12*2048*128*2 =  6,291,456
  unsigned short* Kp = (unsigned short*)(ws + opB + 6291456);    // 12*6144*128*2 = 18,874,368
  unsigned short* Vt = (unsigned short*)(ws + opB + 25165824);   // 12*64*6144*2  =  9,437,184
  float*          Ml = (float*)(ws + opB + 34603008);            // 12*8*2048*2*4 = 1,572,864
                                                                 // total 61,341,696 bytes

  k_setup<<<3504, 256, 0, stream>>>(ehr, ehrb, Wq, Wk, Wv, Wt);
  k_gemm_fused<<<8352, 256, 0, stream>>>(ehrb, missing, exist, Wt, bq, bk, bv,
                                         Qp, Kp, Vt, cooc, ehr, out);
  k_attn<8><<<HEADS * 8 * 16, 256, 0, stream>>>(Qp, Kp, Vt, Op, Ml);
  k_merge<<<HEADS * M_MISS * 16 / 256, 256, 0, stream>>>(Op, Ml, missing, out, ns);
}

// Round 18
// 125.060 us; speedup vs baseline: 1.0160x; 1.0160x over previous
//
#include <hip/hip_runtime.h>

typedef __attribute__((ext_vector_type(8))) short short8;
typedef __attribute__((ext_vector_type(8))) _Float16 half8;
typedef __attribute__((ext_vector_type(4))) float f32x4;
typedef __attribute__((ext_vector_type(16))) float f32x16;
typedef __attribute__((ext_vector_type(4))) unsigned short us4;
typedef __attribute__((ext_vector_type(4))) unsigned int u32x4;

#define MFMA16(a,b,c)  __builtin_amdgcn_mfma_f32_16x16x32_bf16(a,b,c,0,0,0)
#define MFMA32(a,b,c)  __builtin_amdgcn_mfma_f32_32x32x16_bf16(a,b,c,0,0,0)
#define MFMA32H(a,b,c) __builtin_amdgcn_mfma_f32_32x32x16_f16(a,b,c,0,0,0)

#define EMBED 768
#define HEADS 12
#define DK 64
#define M_MISS 2048
#define N_EX 6144
#define NSEC 8192
#define DPHY 128              // physical packed dim: [0,64)=proj bf16, [64,128)=bias f16
#define QSC 0.125f            // Q-side scale (natural-log domain; __expf native exp path)
#define THR 7.0f              // defer-max threshold (P <= e^7 ~ 1100)

// direct global->LDS, 16B per lane; dest = wave-uniform base + lane*16
#define GLOAD16(g, l) __builtin_amdgcn_global_load_lds( \
    (const __attribute__((address_space(1))) unsigned int*)(g), \
    (__attribute__((address_space(3))) unsigned int*)(l), 16, 0, 0)

__device__ __forceinline__ unsigned short f2bf(float f){
  unsigned u = __builtin_bit_cast(unsigned, f);
  u += 0x7FFFu + ((u >> 16) & 1u);
  return (unsigned short)(u >> 16);
}
__device__ __forceinline__ unsigned short f2h(float f){
  _Float16 h = (_Float16)f;      // RNE, 10 mantissa bits — 8x tighter than bf16
  return __builtin_bit_cast(unsigned short, h);
}
__device__ __forceinline__ float max3(float a, float b, float c){
  return fmaxf(fmaxf(a, b), c);  // clang fuses to v_max3_f32
}

// ---------------- setup: ehrb <- bf16(ehr), Wt transpose (gemm dependencies ONLY) ----------------
__global__ __launch_bounds__(256) void k_setup(
    const float* __restrict__ ehr, unsigned short* __restrict__ ehrb,
    const float* __restrict__ Wq, const float* __restrict__ Wk,
    const float* __restrict__ Wv, unsigned short* __restrict__ Wt)
{
  __shared__ float tile[64][65];
  int b = blockIdx.x, tid = threadIdx.x;
  if (b < 3072) {
    long g = (long)b * 256 + tid;
    float4 v0 = *reinterpret_cast<const float4*>(&ehr[g * 8]);
    float4 v1 = *reinterpret_cast<const float4*>(&ehr[g * 8 + 4]);
    short8 p;
    p[0]=(short)f2bf(v0.x); p[1]=(short)f2bf(v0.y); p[2]=(short)f2bf(v0.z); p[3]=(short)f2bf(v0.w);
    p[4]=(short)f2bf(v1.x); p[5]=(short)f2bf(v1.y); p[6]=(short)f2bf(v1.z); p[7]=(short)f2bf(v1.w);
    *reinterpret_cast<short8*>(&ehrb[g * 8]) = p;
    return;
  }
  int bid = b - 3072;
  int which = bid / 144, t = bid % 144;
  int er0 = (t / 12) * 64, cc0 = (t % 12) * 64;
  const float* W = (which == 0) ? Wq : ((which == 1) ? Wk : Wv);
  unsigned short* dst = Wt + (long)which * EMBED * EMBED;
  {
    int e = tid >> 4, c4 = (tid & 15) * 4;
    for (int i = 0; i < 4; i++) {
      float4 v = *reinterpret_cast<const float4*>(&W[(long)(er0 + e + i*16) * EMBED + cc0 + c4]);
      tile[e + i*16][c4 + 0] = v.x; tile[e + i*16][c4 + 1] = v.y;
      tile[e + i*16][c4 + 2] = v.z; tile[e + i*16][c4 + 3] = v.w;
    }
  }
  __syncthreads();
  {
    int c = tid >> 4, e4 = (tid & 15) * 4;
    for (int i = 0; i < 4; i++) {
      us4 u;
      for (int j = 0; j < 4; j++) u[j] = f2bf(tile[e4 + j][c + i*16]);
      *reinterpret_cast<us4*>(&dst[(long)(cc0 + c + i*16) * EMBED + er0 + e4]) = u;
    }
  }
}

// ---------------- fused gather-GEMM + (appended) cooc f16 pack + exist-rows out copy ----------------
// [0,672): Q/K/V gemm. [672,2208): Qp cooc pack. [2208,6816): Kp cooc pack.
// [6816,8352): out[exist rows] <- ehr (missing rows written later by k_merge — race-free).
__global__ __launch_bounds__(256) void k_gemm_fused(
    const unsigned short* __restrict__ ehrb,
    const int* __restrict__ missing, const int* __restrict__ exist,
    const unsigned short* __restrict__ Wt,
    const float* __restrict__ bq, const float* __restrict__ bk, const float* __restrict__ bv,
    unsigned short* __restrict__ Qp, unsigned short* __restrict__ Kp, unsigned short* __restrict__ Vt,
    const float* __restrict__ cooc, const float* __restrict__ ehr, float* __restrict__ out)
{
  __shared__ unsigned char sA[2][8192];   // 128 rows x 32 bf16 (64B rows), chunk-swizzled
  __shared__ unsigned char sB[2][8192];
  int bid = blockIdx.x;
  int tid = threadIdx.x;

  if (bid >= 6816) {       // exist-rows copy: 1536 blocks x 4 rows
    int t4 = (bid - 6816) * 4 + (tid >> 6);
    long row = exist[t4];
    const f32x4* s = reinterpret_cast<const f32x4*>(ehr + row * EMBED);
    f32x4* d = reinterpret_cast<f32x4*>(out + row * EMBED);
    int l = tid & 63;
    d[l] = s[l]; d[l + 64] = s[l + 64]; d[l + 128] = s[l + 128];
    return;
  }
  if (bid >= 672) {        // cooc f16 pack into dims [64,128) of Qp/Kp
    const int* idx; unsigned short* dst; int count; int g;
    if (bid < 2208) { idx = missing; dst = Qp; count = M_MISS; g = (bid -  672) * 256 + tid; }
    else            { idx = exist;   dst = Kp; count = N_EX;   g = (bid - 2208) * 256 + tid; }
    int d4 = (g & 15) * 4;
    int r  = (g >> 4) % count;
    int h  = (g >> 4) / count;
    int src_row = idx[r];
    float4 v = *reinterpret_cast<const float4*>(&cooc[((long)h * NSEC + src_row) * DK + d4]);
    us4 hf;
    hf[0] = f2h(v.x); hf[1] = f2h(v.y); hf[2] = f2h(v.z); hf[3] = f2h(v.w);
    long base = ((long)h * count + r) * DPHY;
    *reinterpret_cast<us4*>(&dst[base + 64 + d4]) = hf;
    return;
  }

  int mode, row0, col0;
  const int* idx; const unsigned short* W; const float* bias;
  if (bid < 96)       { mode = 0; idx = missing; W = Wt;              bias = bq;
                        row0 = (bid & 15) * 128; col0 = (bid >> 4) * 128; }
  else if (bid < 384) { int t = bid - 96;  mode = 1; idx = exist; W = Wt + 589824;     bias = bk;
                        row0 = (t % 48) * 128; col0 = (t / 48) * 128; }
  else                { int t = bid - 384; mode = 2; idx = exist; W = Wt + 2 * 589824; bias = bv;
                        row0 = (t % 48) * 128; col0 = (t / 48) * 128; }

  int wv4 = tid >> 6, lane = tid & 63, l15 = lane & 15, lg = lane >> 4;
  int wm = wv4 >> 1, wn = wv4 & 1;

  int ar = tid >> 2, sl = tid & 3;
  int aoff = (sl ^ (ar & 3)) << 3;                     // element offset within row
  long gA0 = (long)idx[row0 + ar] * EMBED + aoff;
  long gA1 = (long)idx[row0 + ar + 64] * EMBED + aoff; // (ar+64)&3 == ar&3
  long gB0 = (long)(col0 + ar) * EMBED + aoff;
  long gB1 = gB0 + (long)64 * EMBED;

  f32x4 acc[4][4];
  #pragma unroll
  for (int i = 0; i < 4; i++)
    #pragma unroll
    for (int j = 0; j < 4; j++) acc[i][j] = (f32x4){0.f,0.f,0.f,0.f};

  #define STAGE_G(buf, k0) do { \
    GLOAD16(ehrb + gA0 + (k0), &sA[buf][wv4 * 1024]); \
    GLOAD16(ehrb + gA1 + (k0), &sA[buf][4096 + wv4 * 1024]); \
    GLOAD16(W + gB0 + (k0), &sB[buf][wv4 * 1024]); \
    GLOAD16(W + gB1 + (k0), &sB[buf][4096 + wv4 * 1024]); \
  } while (0)

  STAGE_G(0, 0);
  __syncthreads();
  int cur = 0;
  for (int ks = 0; ks < 24; ks++) {
    if (ks < 23) STAGE_G(cur ^ 1, (ks + 1) * 32);
    short8 a[4], b[4];
    #pragma unroll
    for (int i = 0; i < 4; i++) {
      unsigned r = (unsigned)(wm * 64 + 16 * i + l15);
      a[i] = *reinterpret_cast<const short8*>(&sA[cur][r * 64 + (((unsigned)lg ^ (r & 3)) << 4)]);
      unsigned c = (unsigned)(wn * 64 + 16 * i + l15);
      b[i] = *reinterpret_cast<const short8*>(&sB[cur][c * 64 + (((unsigned)lg ^ (c & 3)) << 4)]);
    }
    #pragma unroll
    for (int i = 0; i < 4; i++)
      #pragma unroll
      for (int j = 0; j < 4; j++)
        acc[i][j] = MFMA16(a[i], b[j], acc[i][j]);
    __syncthreads();
    cur ^= 1;
  }
  #undef STAGE_G

  #pragma unroll
  for (int i = 0; i < 4; i++) {
    int mrow = row0 + wm * 64 + 16 * i + lg * 4;
    #pragma unroll
    for (int j = 0; j < 4; j++) {
      int cg = col0 + wn * 64 + 16 * j + l15;
      float bv_ = bias[cg];
      int h = cg >> 6, d = cg & 63;
      if (mode == 2) {
        us4 u;
        #pragma unroll
        for (int r = 0; r < 4; r++) u[r] = f2bf(acc[i][j][r] + bv_);
        *reinterpret_cast<us4*>(&Vt[((long)h * 64 + d) * N_EX + mrow]) = u;
      } else if (mode == 0) {
        #pragma unroll
        for (int r = 0; r < 4; r++)
          Qp[((long)h * M_MISS + mrow + r) * DPHY + d] = f2bf((acc[i][j][r] + bv_) * QSC);
      } else {
        #pragma unroll
        for (int r = 0; r < 4; r++)
          Kp[((long)h * N_EX + mrow + r) * DPHY + d] = f2bf(acc[i][j][r] + bv_);
      }
    }
  }
}

// ---------------- flash attention: swapped 32x32 MFMA, in-register softmax ----------------
// FINAL measured-best config (r14/r16: 125.1-125.3us total, k_attn 78.4-78.5us).
// Occupancy is unified-regfile-bound (84 arch + ~64 acc ≈ 148/wave -> 3 waves/SIMD);
// grid/split/dbuf/setprio/bounds variations all measured neutral-to-negative (r7/8/9/15/17).
// D_qk physical 128: proj 4 chunks bf16 + bias 4 chunks f16. 4-bit K swizzle.
// P^T redistribute via v_permlane32_swap_b32. __expf softmax, defer-max THR=7.
template<int NS>
__global__ __launch_bounds__(256, 3) void k_attn(
    const unsigned short* __restrict__ Qp, const unsigned short* __restrict__ Kp,
    const unsigned short* __restrict__ Vt,
    float* __restrict__ Opart, float* __restrict__ ML)
{
  // XCD-chunked swizzle: nwg = 192*NS, divisible by 8
  constexpr int NSLc = N_EX / NS;
  constexpr int ITERS = NSLc / 64;
  int cpx = 24 * NS;
  int wg = (blockIdx.x & 7) * cpx + (blockIdx.x >> 3);
  int per_h = NS << 4;
  int h  = wg / per_h;
  int rem = wg - h * per_h;
  int sp = rem >> 4;
  int qb = rem & 15;
  int tid = threadIdx.x;
  int wv = tid >> 6, lane = tid & 63, l31 = lane & 31, hh = lane >> 5;

  __shared__ unsigned char sK[64 * 256];   // 64 n-rows x 128 shorts (16 chunks), 4-bit swizzle: 16KB
  __shared__ unsigned char sV[64 * 128];   // 64 d-rows x  64 bf16  ( 8 chunks), 3-bit swizzle:  8KB

  int koff[4];
  #pragma unroll
  for (int i = 0; i < 4; i++) {
    int s = i * 256 + tid;
    int row = s >> 4, slt = s & 15;
    koff[i] = row * DPHY + ((slt ^ (row & 15)) << 3);
  }
  int voff[2];
  #pragma unroll
  for (int i = 0; i < 2; i++) {
    int s = i * 256 + tid;
    int row = s >> 3, slt = s & 7;
    voff[i] = row * N_EX + ((slt ^ (row & 7)) << 3);
  }
  const unsigned short* kti0 = Kp + ((long)h * N_EX + sp * NSLc) * DPHY;
  const unsigned short* vti0 = Vt + (long)h * 64 * N_EX + sp * NSLc;

  int mbase = qb * 128 + wv * 32;
  int m = mbase + l31;

  short8 qg[8];
  {
    const unsigned short* qrow = Qp + ((long)h * M_MISS + m) * DPHY + hh * 8;
    #pragma unroll
    for (int g = 0; g < 8; g++)
      qg[g] = *reinterpret_cast<const short8*>(qrow + g * 16);
  }

  f32x16 oacc[2];
  #pragma unroll
  for (int dt = 0; dt < 2; dt++)
    #pragma unroll
    for (int r = 0; r < 16; r++) oacc[dt][r] = 0.f;
  float m_run = -3.0e38f, l_run = 0.f;

  for (int it = 0; it < ITERS; ++it) {
    __syncthreads();   // all waves done reading previous tile
    {
      const unsigned short* kt_ = kti0 + (long)it * 64 * DPHY;
      GLOAD16(kt_ + koff[0], &sK[(0 * 4 + wv) * 1024]);
      GLOAD16(kt_ + koff[1], &sK[(1 * 4 + wv) * 1024]);
      GLOAD16(kt_ + koff[2], &sK[(2 * 4 + wv) * 1024]);
      GLOAD16(kt_ + koff[3], &sK[(3 * 4 + wv) * 1024]);
      const unsigned short* vt_ = vti0 + it * 64;
      GLOAD16(vt_ + voff[0], &sV[(0 * 4 + wv) * 1024]);
      GLOAD16(vt_ + voff[1], &sV[(1 * 4 + wv) * 1024]);
    }
    __syncthreads();   // drains vmcnt: tile ready

    // S^T: 2 n-tiles of 32 rows. A = K chunk (row n=l31), B = qg (col m=l31).
    // chunks 0-3: proj bf16; chunks 4-7: bias f16 (same fp32 accumulator).
    f32x16 st[2];
    #pragma unroll
    for (int nt = 0; nt < 2; nt++) {
      #pragma unroll
      for (int r = 0; r < 16; r++) st[nt][r] = 0.f;
      unsigned nrow = (unsigned)(nt * 32 + l31);
      const unsigned char* kb = &sK[nrow * 256];
      unsigned px = nrow & 15;
      #define KRD(g) (*reinterpret_cast<const short8*>(kb + ((((unsigned)(2*(g)+hh)) ^ px) << 4)))
      short8 kf;
      kf = KRD(0); st[nt] = MFMA32(kf, qg[0], st[nt]);
      kf = KRD(1); st[nt] = MFMA32(kf, qg[1], st[nt]);
      kf = KRD(2); st[nt] = MFMA32(kf, qg[2], st[nt]);
      kf = KRD(3); st[nt] = MFMA32(kf, qg[3], st[nt]);
      kf = KRD(4); st[nt] = MFMA32H(__builtin_bit_cast(half8, kf), __builtin_bit_cast(half8, qg[4]), st[nt]);
      kf = KRD(5); st[nt] = MFMA32H(__builtin_bit_cast(half8, kf), __builtin_bit_cast(half8, qg[5]), st[nt]);
      kf = KRD(6); st[nt] = MFMA32H(__builtin_bit_cast(half8, kf), __builtin_bit_cast(half8, qg[6]), st[nt]);
      kf = KRD(7); st[nt] = MFMA32H(__builtin_bit_cast(half8, kf), __builtin_bit_cast(half8, qg[7]), st[nt]);
      #undef KRD
    }

    // in-register online softmax (natural domain, native __expf), defer-max; v_max3 tree
    float t0 = max3(max3(st[0][0],  st[0][1],  st[0][2]),
                    max3(st[0][3],  st[0][4],  st[0][5]),
                    max3(st[0][6],  st[0][7],  st[0][8]));
    float t1 = max3(max3(st[0][9],  st[0][10], st[0][11]),
                    max3(st[0][12], st[0][13], st[0][14]),
                    max3(st[0][15], st[1][0],  st[1][1]));
    float t2 = max3(max3(st[1][2],  st[1][3],  st[1][4]),
                    max3(st[1][5],  st[1][6],  st[1][7]),
                    max3(st[1][8],  st[1][9],  st[1][10]));
    float t3 = max3(max3(st[1][11], st[1][12], st[1][13]),
                    fmaxf(st[1][14], st[1][15]), t0);
    float mx = max3(t1, t2, t3);
    mx = fmaxf(mx, __shfl_xor(mx, 32));
    if (!__all(mx <= m_run + THR)) {
      float mn = fmaxf(m_run, mx);
      float sc = __expf(m_run - mn);
      m_run = mn;
      l_run *= sc;
      #pragma unroll
      for (int dt = 0; dt < 2; dt++)
        #pragma unroll
        for (int r = 0; r < 16; r++) oacc[dt][r] *= sc;
    }
    float lsum = 0.f;
    unsigned c[2][4][2];   // c[nt][jj][i] = bf16pair P(nt*32+8jj+4hh+2i, +1)
    #pragma unroll
    for (int nt = 0; nt < 2; nt++) {
      float p[16];
      #pragma unroll
      for (int r = 0; r < 16; r++) { p[r] = __expf(st[nt][r] - m_run); lsum += p[r]; }
      #pragma unroll
      for (int jj = 0; jj < 4; jj++) {
        asm("v_cvt_pk_bf16_f32 %0, %1, %2" : "=v"(c[nt][jj][0]) : "v"(p[4*jj+0]), "v"(p[4*jj+1]));
        asm("v_cvt_pk_bf16_f32 %0, %1, %2" : "=v"(c[nt][jj][1]) : "v"(p[4*jj+2]), "v"(p[4*jj+3]));
      }
    }
    lsum += __shfl_xor(lsum, 32);
    l_run += lsum;

    // P^T B-frags via permlane32_swap: newA={A_lo,B_lo}, newB={A_hi,B_hi}
    short8 pf[2][2];
    #pragma unroll
    for (int nt = 0; nt < 2; nt++)
      #pragma unroll
      for (int ks = 0; ks < 2; ks++) {
        unsigned a0 = c[nt][2*ks][0], b0 = c[nt][2*ks+1][0];
        unsigned a1 = c[nt][2*ks][1], b1 = c[nt][2*ks+1][1];
        asm("v_permlane32_swap_b32 %0, %1" : "+v"(a0), "+v"(b0));
        asm("v_permlane32_swap_b32 %0, %1" : "+v"(a1), "+v"(b1));
        u32x4 w;
        w[0] = a0; w[1] = a1; w[2] = b0; w[3] = b1;
        pf[nt][ks] = __builtin_bit_cast(short8, w);
      }

    // O^T += V^T . P^T : A = V^T (row d=l31), B = pf. 8 MFMAs.
    #pragma unroll
    for (int dt = 0; dt < 2; dt++) {
      unsigned drow = (unsigned)(dt * 32 + l31);
      const unsigned char* vb = &sV[drow * 128];
      unsigned pd = drow & 7;
      #pragma unroll
      for (int nt = 0; nt < 2; nt++)
        #pragma unroll
        for (int ks = 0; ks < 2; ks++) {
          short8 vf = *reinterpret_cast<const short8*>(vb + ((((unsigned)(nt*4+ks*2+hh)) ^ pd) << 4));
          oacc[dt] = MFMA32(vf, pf[nt][ks], oacc[dt]);
        }
    }
  }

  // epilogue: O^T reg r -> d = dt*32 + 8*(r>>2) + 4*hh + (r&3); m = mbase+l31
  long pbase = ((long)(h * NS + sp)) * M_MISS;
  if (hh == 0) {
    float2 v; v.x = m_run; v.y = l_run;
    *reinterpret_cast<float2*>(&ML[(pbase + m) * 2]) = v;
  }
  #pragma unroll
  for (int dt = 0; dt < 2; dt++)
    #pragma unroll
    for (int rq = 0; rq < 4; rq++) {
      f32x4 o4;
      o4[0] = oacc[dt][4*rq + 0]; o4[1] = oacc[dt][4*rq + 1];
      o4[2] = oacc[dt][4*rq + 2]; o4[3] = oacc[dt][4*rq + 3];
      *reinterpret_cast<f32x4*>(&Opart[(pbase + m) * 64 + dt * 32 + 8 * rq + 4 * hh]) = o4;
    }
}

// ---------------- merge split-KV partials, scatter to out (writes ONLY missing rows) ----------------
__global__ __launch_bounds__(256) void k_merge(
    const float* __restrict__ Opart, const float* __restrict__ ML,
    const int* __restrict__ missing, float* __restrict__ out, int ns)
{
  int g = blockIdx.x * 256 + threadIdx.x;   // HEADS*M_MISS*16
  int d4 = (g & 15) * 4;
  int row = g >> 4;
  int m = row & (M_MISS - 1), h = row >> 11;
  long b0 = (long)h * ns * M_MISS + m;
  float M = -3.0e38f;
  for (int sp = 0; sp < ns; sp++)
    M = fmaxf(M, ML[(b0 + (long)sp * M_MISS) * 2]);
  float L = 0.f;
  f32x4 o = (f32x4){0.f,0.f,0.f,0.f};
  for (int sp = 0; sp < ns; sp++) {
    float2 v = *reinterpret_cast<const float2*>(&ML[(b0 + (long)sp * M_MISS) * 2]);
    float w = __expf(v.x - M);
    L += v.y * w;
    f32x4 t = *reinterpret_cast<const f32x4*>(&Opart[(b0 + (long)sp * M_MISS) * 64 + d4]);
    o += t * w;
  }
  float inv = 1.0f / L;
  int orow = missing[m];
  *reinterpret_cast<f32x4*>(&out[(long)orow * EMBED + h * 64 + d4]) = o * inv;
}

extern "C" void kernel_launch(void* const* d_in, const int* in_sizes, int n_in,
                              void* d_out, int out_size, void* d_ws, size_t ws_size,
                              hipStream_t stream) {
  const float* ehr     = (const float*)d_in[0];
  const int*   exist   = (const int*)  d_in[1];
  const int*   missing = (const int*)  d_in[2];
  const float* Wq = (const float*)d_in[3];
  const float* bq = (const float*)d_in[4];
  const float* Wk = (const float*)d_in[5];
  const float* bk = (const float*)d_in[6];
  const float* Wv = (const float*)d_in[7];
  const float* bv = (const float*)d_in[8];
  const float* cooc = (const float*)d_in[9];
  float* out = (float*)d_out;

  const int ns = 4;   // measured-best split

  char* ws = (char*)d_ws;
  size_t opB = (size_t)HEADS * ns * M_MISS * 64 * 4;   // fp32 partials (25,165,824)
  // Wt (3.54 MB) + ehrb (12.6 MB) alias inside Opart's region (dead before k_attn writes Op).
  unsigned short* Wt   = (unsigned short*)(ws);                  // [0, 3,538,944)
  unsigned short* ehrb = (unsigned short*)(ws + 3538944);        // [3,538,944, 16,121,856)
  float*          Op   = (float*)(ws);
  unsigned short* Qp = (unsigned short*)(ws + opB);              // 12*2048*128*2 =  6,291,456
  unsigned short* Kp = (unsigned short*)(ws + opB + 6291456);    // 12*6144*128*2 = 18,874,368
  unsigned short* Vt = (unsigned short*)(ws + opB + 25165824);   // 12*64*6144*2  =  9,437,184
  float*          Ml = (float*)(ws + opB + 34603008);            // 786,432  (total 60,555,264)

  k_setup<<<3504, 256, 0, stream>>>(ehr, ehrb, Wq, Wk, Wv, Wt);
  k_gemm_fused<<<8352, 256, 0, stream>>>(ehrb, missing, exist, Wt, bq, bk, bv,
                                         Qp, Kp, Vt, cooc, ehr, out);
  k_attn<4><<<HEADS * 4 * 16, 256, 0, stream>>>(Qp, Kp, Vt, Op, Ml);
  k_merge<<<HEADS * M_MISS * 16 / 256, 256, 0, stream>>>(Op, Ml, missing, out, ns);
}